// Round 10
// baseline (415.993 us; speedup 1.0000x reference)
//
#include <hip/hip_runtime.h>
#include <hip/hip_fp8.h>

#define N_ROWS 4096
#define H_DIM  1024
#define V_SIZE 32000

typedef int   i32x4 __attribute__((ext_vector_type(4)));
typedef int   i32x8 __attribute__((ext_vector_type(8)));
typedef float f32x4 __attribute__((ext_vector_type(4)));

typedef __attribute__((address_space(1))) void* gas_ptr;
typedef __attribute__((address_space(3))) void* las_ptr;

__global__ void zero_f32(float* __restrict__ p, int n) {
  int i = blockIdx.x * blockDim.x + threadIdx.x;
  if (i < n) p[i] = 0.0f;
}

__device__ __forceinline__ unsigned pk4_fp8(float a, float b, float c, float d) {
#if __has_builtin(__builtin_amdgcn_cvt_pk_fp8_f32)
  int v = __builtin_amdgcn_cvt_pk_fp8_f32(a, b, 0, false);
  v = __builtin_amdgcn_cvt_pk_fp8_f32(c, d, v, true);
  return (unsigned)v;
#else
  __hip_fp8_e4m3 qa(a), qb(b), qc(c), qd(d);
  return (unsigned)qa.__x | ((unsigned)qb.__x << 8) | ((unsigned)qc.__x << 16) |
         ((unsigned)qd.__x << 24);
#endif
}

// fp32 -> fp8 e4m3 with the LDS swizzle PRE-BAKED into the HBM layout:
// out[row*1024 + (k ^ ((row&7)<<4))] = fp8(in[row*1024 + k]).
__global__ void cvt_fp8(const float* __restrict__ in, unsigned char* __restrict__ out, int total16) {
  int idx = blockIdx.x * blockDim.x + threadIdx.x;
  int stride = gridDim.x * blockDim.x;
  for (; idx < total16; idx += stride) {
    unsigned row = (unsigned)idx >> 6;          // H_DIM/16 = 64 chunks per row
    unsigned k0 = ((unsigned)idx & 63u) << 4;
    const float4* p = (const float4*)(in + (size_t)row * H_DIM + k0);
    float4 f0 = p[0], f1 = p[1], f2 = p[2], f3 = p[3];
    unsigned long long u0 = (unsigned long long)pk4_fp8(f0.x, f0.y, f0.z, f0.w) |
                            ((unsigned long long)pk4_fp8(f1.x, f1.y, f1.z, f1.w) << 32);
    unsigned long long u1 = (unsigned long long)pk4_fp8(f2.x, f2.y, f2.z, f2.w) |
                            ((unsigned long long)pk4_fp8(f3.x, f3.y, f3.z, f3.w) << 32);
    unsigned key = (row & 7u) << 4;
    unsigned char* ob = out + (size_t)row * H_DIM;
    *(unsigned long long*)(ob + (k0 ^ key)) = u0;
    *(unsigned long long*)(ob + ((k0 ^ key) + 8u)) = u1;
  }
}

__device__ __forceinline__ i32x8 cat8(i32x4 a, i32x4 b) {
  return __builtin_shufflevector(a, b, 0, 1, 2, 3, 4, 5, 6, 7);
}

// MX-scaled fp8 MFMA, unit scales (E8M0 127 = x1.0): numerically identical to
// plain e4m3 matmul at the 4661 TF MX rate. Validated r8/r9.
__device__ __forceinline__ f32x4 mx_mfma(i32x8 a, i32x8 b, f32x4 c) {
  return __builtin_amdgcn_mfma_scale_f32_16x16x128_f8f6f4(
      a, b, c, 0 /*A=fp8*/, 0 /*B=fp8*/, 0, 0x7f7f7f7f, 0, 0x7f7f7f7f);
}

#define PHASE_FENCE() do { \
    asm volatile("s_waitcnt vmcnt(0)" ::: "memory"); \
    __builtin_amdgcn_sched_barrier(0); \
    __builtin_amdgcn_s_barrier(); \
    __builtin_amdgcn_sched_barrier(0); \
  } while (0)

// Fused dual-GEMM (MX-fp8 16x16x128) + KL partial sums, 2-phase pipeline.
// Student tiles {x,Ws} and teacher tiles {tx,Wt} are DISJOINT LDS regions, so
// each k-step splits into: phase A = compute student while teacher staging
// (issued at A's start by waves 1,3) is in flight; phase B = compute teacher
// while waves 0,2 issue NEXT step's student staging. Per-wave vmcnt(0) drains
// cover loads issued a full phase earlier -> latency hidden, no extra LDS.
// ds_read stream identical to r9 (HW-verified 0 bank conflicts).
__global__ __launch_bounds__(256, 2) void fused_kl(
    const unsigned char* __restrict__ x8, const unsigned char* __restrict__ tx8,
    const unsigned char* __restrict__ ws8, const unsigned char* __restrict__ wt8,
    float* __restrict__ Zt, float* __restrict__ Uu, float* __restrict__ Zs) {
  __shared__ __align__(16) char smem[65536];  // x | tx (+16KB) | Ws (+32KB) | Wt (+48KB)

  const unsigned tid = threadIdx.x;
  const unsigned lane = tid & 63u;
  const unsigned w = tid >> 6;
  const unsigned wr = w >> 1, wc = w & 1;

  const unsigned b = blockIdx.x;
  const unsigned rb = (b & 7u) * 4u + ((b >> 3) & 3u);  // row-block 0..31
  const unsigned chunk = b >> 5;                        // vocab chunk 0..15
  const unsigned row0 = rb * 128u;
  const unsigned t_begin = chunk * 15u + (chunk < 10u ? chunk : 10u);
  const unsigned t_count = (chunk < 10u) ? 16u : 15u;
  const unsigned NK = t_count * 8u;  // flattened (vt,kt) steps

  const unsigned c = lane & 15u;        // fragment row/col index
  const unsigned g = (lane >> 4) & 3u;  // K-group
  const unsigned key = (c & 7u) << 4;   // swizzle key (bits 4-6)

  // Loop-invariant ds_read base pointers (r9-identical address stream).
  const char* pA[2];
  const char* pB[2];
#pragma unroll
  for (int kk2 = 0; kk2 < 2; ++kk2) {
    unsigned f = (((unsigned)kk2 << 6) | (g << 4)) ^ key;
    pA[kk2] = smem + (wr * 64u + c) * 128u + f;
    pB[kk2] = smem + 32768u + (wc * 64u + c) * 128u + f;
  }

  // Staging: wave w owns one tile. w0:x w2:Ws (student group), w1:tx w3:Wt
  // (teacher group). Pre-swizzled source, linear LDS dest.
  char* sdst = smem + w * 16384u + lane * 16u;
  const unsigned char* gsrc = (w == 0) ? x8 : (w == 1) ? tx8 : (w == 2) ? ws8 : wt8;
  const bool a_wave = (w < 2);
  const bool s_wave = (w == 0) || (w == 2);
  const unsigned srow = lane >> 3;
  const unsigned sb = (lane & 7u) * 16u;

  auto issue_stage = [&](unsigned step) {
    unsigned vtp = step >> 3, ktp = step & 7u;
    unsigned trow = a_wave ? row0 : (t_begin + vtp) * 128u;
    const unsigned char* s0 = gsrc + (size_t)(trow + srow) * H_DIM + sb + ktp * 128u;
#pragma unroll
    for (unsigned i = 0; i < 16; ++i)
      __builtin_amdgcn_global_load_lds((gas_ptr)(s0 + (size_t)i * (8u * H_DIM)),
                                       (las_ptr)(sdst + i * 1024u), 16, 0, 0);
  };

  float zt1 = 0.f, uu1 = 0.f, zs1 = 0.f;
  const f32x4 fzero = {0.f, 0.f, 0.f, 0.f};
  f32x4 acc_s[4][4], acc_t[4][4];

  // Prologue: student tiles for step 0.
  if (s_wave) issue_stage(0);
  PHASE_FENCE();

  for (unsigned t = 0; t < NK; ++t) {
    const unsigned kt = t & 7u;
    if (kt == 0u) {
#pragma unroll
      for (int mi = 0; mi < 4; ++mi)
#pragma unroll
        for (int ni = 0; ni < 4; ++ni) { acc_s[mi][ni] = fzero; acc_t[mi][ni] = fzero; }
    }

    // ---- phase A: teacher staging (this step) in flight; student compute ----
    if (!s_wave) issue_stage(t);
    {
      i32x8 ax[4];
#pragma unroll
      for (int mi = 0; mi < 4; ++mi)
        ax[mi] = cat8(*(const i32x4*)(pA[0] + mi * 2048),
                      *(const i32x4*)(pA[1] + mi * 2048));
      __builtin_amdgcn_s_setprio(1);
#pragma unroll
      for (int ni = 0; ni < 4; ++ni) {
        i32x8 bs = cat8(*(const i32x4*)(pB[0] + ni * 2048),
                        *(const i32x4*)(pB[1] + ni * 2048));
#pragma unroll
        for (int mi = 0; mi < 4; ++mi)
          acc_s[mi][ni] = mx_mfma(ax[mi], bs, acc_s[mi][ni]);
      }
      __builtin_amdgcn_s_setprio(0);
    }
    PHASE_FENCE();  // teacher tiles staged; student reads done

    // ---- phase B: student staging (next step) in flight; teacher compute ----
    if (s_wave && t + 1u < NK) issue_stage(t + 1u);
    {
      i32x8 at[4];
#pragma unroll
      for (int mi = 0; mi < 4; ++mi)
        at[mi] = cat8(*(const i32x4*)(pA[0] + mi * 2048 + 16384),
                      *(const i32x4*)(pA[1] + mi * 2048 + 16384));
      __builtin_amdgcn_s_setprio(1);
#pragma unroll
      for (int ni = 0; ni < 4; ++ni) {
        i32x8 bt = cat8(*(const i32x4*)(pB[0] + ni * 2048 + 16384),
                        *(const i32x4*)(pB[1] + ni * 2048 + 16384));
#pragma unroll
        for (int mi = 0; mi < 4; ++mi)
          acc_t[mi][ni] = mx_mfma(at[mi], bt, acc_t[mi][ni]);
      }
      __builtin_amdgcn_s_setprio(0);
    }

    // ---- per-vocab-tile epilogue (registers only; overlaps other block) ----
    if (kt == 7u) {
      // C/D layout: col = lane&15, row = (lane>>4)*4 + j (m89-verified)
#pragma unroll
      for (int mi = 0; mi < 4; ++mi)
#pragma unroll
        for (int j = 0; j < 4; ++j) {
          float ztl = 0.f, uul = 0.f, zsl = 0.f;
#pragma unroll
          for (int ni = 0; ni < 4; ++ni) {
            float s = acc_s[mi][ni][j];
            float tt = acc_t[mi][ni][j];
            float et = __expf(tt);
            ztl += et;
            uul += et * (tt - s);
            zsl += __expf(s);
          }
          ztl += __shfl_xor(ztl, 1); ztl += __shfl_xor(ztl, 2);
          ztl += __shfl_xor(ztl, 4); ztl += __shfl_xor(ztl, 8);
          uul += __shfl_xor(uul, 1); uul += __shfl_xor(uul, 2);
          uul += __shfl_xor(uul, 4); uul += __shfl_xor(uul, 8);
          zsl += __shfl_xor(zsl, 1); zsl += __shfl_xor(zsl, 2);
          zsl += __shfl_xor(zsl, 4); zsl += __shfl_xor(zsl, 8);
          if (c == (unsigned)(mi * 4 + j)) { zt1 += ztl; uu1 += uul; zs1 += zsl; }
        }
    }

    PHASE_FENCE();  // student tiles for t+1 staged; teacher reads done
  }

  // Lane (g,c) owns row: wr*64 + (c>>2)*16 + g*4 + (c&3)  (bijective over 64 rows)
  {
    unsigned n = row0 + wr * 64u + (c >> 2) * 16u + g * 4u + (c & 3u);
    atomicAdd(&Zt[n], zt1);
    atomicAdd(&Uu[n], uu1);
    atomicAdd(&Zs[n], zs1);
  }
}

// KL_n = U/Zt - log Zt + log Zs ; out = mean over N, float32.
__global__ void finalize_kl(const float* __restrict__ Zt, const float* __restrict__ Uu,
                            const float* __restrict__ Zs, float* __restrict__ out) {
  __shared__ float red[4];
  float s = 0.f;
  for (int r = threadIdx.x; r < N_ROWS; r += 256) {
    s += Uu[r] / Zt[r] - __logf(Zt[r]) + __logf(Zs[r]);
  }
  s += __shfl_xor(s, 1); s += __shfl_xor(s, 2); s += __shfl_xor(s, 4);
  s += __shfl_xor(s, 8); s += __shfl_xor(s, 16); s += __shfl_xor(s, 32);
  if ((threadIdx.x & 63) == 0) red[threadIdx.x >> 6] = s;
  __syncthreads();
  if (threadIdx.x == 0) {
    float tot = red[0] + red[1] + red[2] + red[3];
    out[0] = tot / (float)N_ROWS;
  }
}

extern "C" void kernel_launch(void* const* d_in, const int* in_sizes, int n_in,
                              void* d_out, int out_size, void* d_ws, size_t ws_size,
                              hipStream_t stream) {
  const float* x  = (const float*)d_in[0];
  const float* tx = (const float*)d_in[1];
  const float* Ws = (const float*)d_in[2];
  const float* Wt = (const float*)d_in[3];

  char* ws = (char*)d_ws;
  float* Zt = (float*)ws;
  float* Uu = Zt + N_ROWS;
  float* Zs = Uu + N_ROWS;
  unsigned char* x8  = (unsigned char*)(ws + 65536);
  unsigned char* tx8 = x8  + (size_t)N_ROWS * H_DIM;
  unsigned char* ws8 = tx8 + (size_t)N_ROWS * H_DIM;
  unsigned char* wt8 = ws8 + (size_t)V_SIZE * H_DIM;

  zero_f32<<<(3 * N_ROWS) / 256, 256, 0, stream>>>(Zt, 3 * N_ROWS);
  cvt_fp8<<<1024, 256, 0, stream>>>(x,  x8,  N_ROWS * (H_DIM / 16));
  cvt_fp8<<<1024, 256, 0, stream>>>(tx, tx8, N_ROWS * (H_DIM / 16));
  cvt_fp8<<<2048, 256, 0, stream>>>(Ws, ws8, V_SIZE * (H_DIM / 16));
  cvt_fp8<<<2048, 256, 0, stream>>>(Wt, wt8, V_SIZE * (H_DIM / 16));
  fused_kl<<<512, 256, 0, stream>>>(x8, tx8, ws8, wt8, Zt, Uu, Zs);
  finalize_kl<<<1, 256, 0, stream>>>(Zt, Uu, Zs, (float*)d_out);
}